// Round 8
// baseline (255.900 us; speedup 1.0000x reference)
//
#include <hip/hip_runtime.h>

// DCNv1 on MI355X. Deform-GEMM via bf16x3 MFMA (hi/lo split, 3 passes -> ~fp32
// precision), v7: ZERO-LDS / ZERO-BARRIER deform kernel. Each lane bilinear-
// samples exactly the 16 channels its MFMA B-fragment needs (pixel=lane&15,
// ch=(lane>>4)*8 + ks*32), so fragments are built directly in registers.
// Weights are read as fragments from global (147KB total, L1/L2-hot).
// Shapes fixed: B=4, C=64, H=W=128, Cout=64, K=3x3, stride=1, pad=1.

constexpr int B_  = 4;
constexpr int C_  = 64;
constexpr int H_  = 128;
constexpr int W_  = 128;
constexpr int CO_ = 64;
constexpr int K_  = 9;
constexpr int HW_ = H_ * W_;

typedef short bf16x8 __attribute__((ext_vector_type(8)));
typedef float f32x4  __attribute__((ext_vector_type(4)));

#define REP18(M) M(0) M(1) M(2) M(3) M(4) M(5) M(6) M(7) M(8) M(9) M(10) M(11) M(12) M(13) M(14) M(15) M(16) M(17)

// ---------------- workspace layout (float units) ----------------
constexpr size_t XT_OFF   = 0;                                    // NHWC x f32
constexpr size_t OFF_OFF  = XT_OFF + (size_t)B_ * HW_ * C_;       // offsets f32
constexpr size_t WPT2_OFF = OFF_OFF + (size_t)B_ * HW_ * 18;      // w_p^T [c][t][20] f32
constexpr size_t WDH_OFF  = WPT2_OFF + (size_t)C_ * K_ * 20;      // w_d hi bf16 [k][oc][c]
constexpr size_t WDL_OFF  = WDH_OFF + (size_t)K_ * CO_ * C_ / 2;  // w_d lo bf16

__device__ inline short f2bf(float x) {                 // RTN f32->bf16
    unsigned u = __float_as_uint(x);
    return (short)((u + 0x7FFF + ((u >> 16) & 1)) >> 16);
}
__device__ inline float bf2f(short s) {
    return __uint_as_float(((unsigned)(unsigned short)s) << 16);
}

// ---------------- K0a: x NCHW -> NHWC ----------------
__global__ __launch_bounds__(256) void transpose_x_k(const float* __restrict__ x,
                                                     float* __restrict__ xt) {
    __shared__ float tile[64][65];
    int bid = blockIdx.x;           // 1024
    int wt  = bid & 1;
    int h   = (bid >> 1) & 127;
    int b   = bid >> 8;
    int w0  = wt * 64;
    int tid = threadIdx.x;
    int lw = tid & 63, c0 = tid >> 6;
#pragma unroll
    for (int i = 0; i < 16; ++i) {
        int c = c0 * 16 + i;
        tile[c][lw] = x[((b * C_ + c) * H_ + h) * W_ + w0 + lw];
    }
    __syncthreads();
    int lc = tid & 63, wp = tid >> 6;
#pragma unroll
    for (int i = 0; i < 16; ++i) {
        int w = wp * 16 + i;
        xt[((size_t)(b * H_ + h) * W_ + w0 + w) * C_ + lc] = tile[lc][w];
    }
}

// ---------------- K0b: weight prep ----------------
__global__ void transpose_w_k(const float* __restrict__ wd, const float* __restrict__ wp,
                              short* __restrict__ wdh, short* __restrict__ wdl,
                              float* __restrict__ wpt2) {
    int i = blockIdx.x * 256 + threadIdx.x;
    if (i < K_ * CO_ * C_) {               // 36864: [k][oc][c]
        int k  = i / (CO_ * C_);
        int r  = i % (CO_ * C_);
        int oc = r >> 6;
        int c  = r & 63;
        float v = wd[(oc * C_ + c) * K_ + k];
        short h = f2bf(v);
        wdh[i] = h;
        wdl[i] = f2bf(v - bf2f(h));
    }
    if (i < C_ * K_ * 20) {                // 11520
        int j = i % 20;
        int t = (i / 20) % K_;
        int c = i / (20 * K_);
        wpt2[i] = (j < 18) ? wp[((j * C_ + c) * 3 + t / 3) * 3 + (t % 3)] : 0.f;
    }
}

// ---------------- K1: offset conv v5 (unchanged; awaiting its counters) ----------------
__global__ __launch_bounds__(256) void offset_conv_k(const float* __restrict__ x,
                                                     const float* __restrict__ wpt2,
                                                     const float* __restrict__ bp,
                                                     float* __restrict__ off) {
    __shared__ float red[4][64][19];
    int tid = threadIdx.x;
    int pix = tid & 63;
    int cqu = __builtin_amdgcn_readfirstlane(tid >> 6);  // wave-uniform 0..3
    int bid = blockIdx.x;
    int w0  = (bid & 1) * 64;
    int h   = (bid >> 1) & 127;
    int b   = bid >> 8;
    int wo  = w0 + pix;

#define DECL_(i) float a##i = 0.f;
    REP18(DECL_)
#undef DECL_

    int c0 = cqu * 16;
    for (int ci = 0; ci < 16; ++ci) {
        int c = c0 + ci;
        const float* xb = x + (size_t)(b * C_ + c) * HW_;   // SGPR base
        const float* wr = wpt2 + c * 180;                   // SGPR base -> s_load
#pragma unroll
        for (int t = 0; t < 9; ++t) {
            int y  = h + t / 3 - 1;
            int xw = wo + (t % 3) - 1;
            float xv = (y >= 0 && y < H_ && xw >= 0 && xw < W_) ? xb[y * W_ + xw] : 0.f;
            const float* wrow = wr + t * 20;
#define FMA_(i) a##i = fmaf(xv, wrow[i], a##i);
            REP18(FMA_)
#undef FMA_
        }
    }
#define ST_(i) red[cqu][pix][i] = a##i;
    REP18(ST_)
#undef ST_
    __syncthreads();

    size_t base = ((size_t)(b * H_ + h) * W_ + w0) * 18;
#pragma unroll
    for (int it = 0; it < 5; ++it) {
        int idx = it * 256 + tid;
        if (idx < 64 * 18) {
            int p = idx / 18, j = idx % 18;
            float s = red[0][p][j] + red[1][p][j] + red[2][p][j] + red[3][p][j] + bp[j];
            off[base + idx] = s;
        }
    }
}

// ---------------- K2: deform sampling + bf16x3 MFMA GEMM v7 ----------------
// NO LDS, NO BARRIERS. Block = 64 pixels (quarter row effectively: 4 waves x
// 16 pix), wave = 16 pixels x all 64 oc (4 M-tiles). Lane builds its own
// B-fragments by sampling exactly (pixel=lane&15, ch=(lane>>4)*8 + ks*32).
// A-fragments loaded from global wdh/wdl [k][oc][c] (hot in L1/L2).
// Grid = B*HW/64 = 1024, XCD slab swizzle for L2 locality.
__global__ __launch_bounds__(256, 3) void deform_gemm_k(const float* __restrict__ xt,
                                                        const float* __restrict__ off,
                                                        const short* __restrict__ wdh,
                                                        const short* __restrict__ wdl,
                                                        float* __restrict__ out) {
    int tid = threadIdx.x;
    int bid = blockIdx.x;              // 1024
    int xcd = bid & 7;                 // XCD slab swizzle
    int idx = bid >> 3;                // 0..127
    int b   = xcd >> 1;
    int h   = ((xcd & 1) << 6) | (idx >> 1);
    int w0  = (idx & 1) * 64;

    int lane = tid & 63;
    int wv   = tid >> 6;               // wave -> 16-pixel group
    int l4   = lane & 15;
    int lq   = lane >> 4;
    int wcol = w0 + wv * 16 + l4;      // this lane's pixel column

    f32x4 acc[4];                      // acc[mt]: oc-tile mt*16..+16
#pragma unroll
    for (int i = 0; i < 4; ++i) acc[i] = (f32x4){0.f, 0.f, 0.f, 0.f};

    // preload this pixel's 9 offset pairs (static-indexed -> VGPRs)
    const float* ob = off + ((size_t)(b * H_ + h) * W_ + wcol) * 18;
    float2 offs[9];
#pragma unroll
    for (int k = 0; k < 9; ++k) offs[k] = *(const float2*)(ob + 2 * k);

    const float* xb  = xt + (size_t)b * HW_ * C_;
    int cb0 = lq * 8;                  // fragment channel base (ks=0)
    const short* wbh = wdh + l4 * 64 + cb0;   // per-lane weight frag base
    const short* wbl = wdl + l4 * 64 + cb0;

#pragma unroll
    for (int k = 0; k < 9; ++k) {
        float2 o2 = offs[k];
        float py = o2.x + (float)(h - 1 + k / 3);
        float px = o2.y + (float)(wcol - 1 + (k % 3));
        float fy = floorf(py), fx = floorf(px);
        float wy = py - fy, wx = px - fx;
        int y0 = (int)fy, x0 = (int)fx;
        int y1 = y0 + 1,  x1 = x0 + 1;
        float w00 = (1.f - wy) * (1.f - wx);
        float w01 = (1.f - wy) * wx;
        float w10 = wy * (1.f - wx);
        float w11 = wy * wx;
        bool vy0 = (y0 >= 0) & (y0 < H_), vy1 = (y1 >= 0) & (y1 < H_);
        bool vx0 = (x0 >= 0) & (x0 < W_), vx1 = (x1 >= 0) & (x1 < W_);
        w00 *= (float)(vy0 & vx0);
        w01 *= (float)(vy0 & vx1);
        w10 *= (float)(vy1 & vx0);
        w11 *= (float)(vy1 & vx1);
        int cy0 = min(max(y0, 0), H_ - 1), cy1 = min(max(y1, 0), H_ - 1);
        int cx0 = min(max(x0, 0), W_ - 1), cx1 = min(max(x1, 0), W_ - 1);
        const float* r00 = xb + ((size_t)cy0 * W_ + cx0) * C_;
        const float* r01 = xb + ((size_t)cy0 * W_ + cx1) * C_;
        const float* r10 = xb + ((size_t)cy1 * W_ + cx0) * C_;
        const float* r11 = xb + ((size_t)cy1 * W_ + cx1) * C_;

        bf16x8 bh[2], bl[2];           // B-frags (hi/lo) for ks=0,1; static-indexed
#pragma unroll
        for (int ks = 0; ks < 2; ++ks) {
            int cb = ks * 32 + cb0;
            float4 a0 = *(const float4*)(r00 + cb), a1 = *(const float4*)(r00 + cb + 4);
            float4 b0 = *(const float4*)(r01 + cb), b1 = *(const float4*)(r01 + cb + 4);
            float4 c0 = *(const float4*)(r10 + cb), c1 = *(const float4*)(r10 + cb + 4);
            float4 d0 = *(const float4*)(r11 + cb), d1 = *(const float4*)(r11 + cb + 4);
            float sv[8];
            sv[0] = w00 * a0.x + w01 * b0.x + w10 * c0.x + w11 * d0.x;
            sv[1] = w00 * a0.y + w01 * b0.y + w10 * c0.y + w11 * d0.y;
            sv[2] = w00 * a0.z + w01 * b0.z + w10 * c0.z + w11 * d0.z;
            sv[3] = w00 * a0.w + w01 * b0.w + w10 * c0.w + w11 * d0.w;
            sv[4] = w00 * a1.x + w01 * b1.x + w10 * c1.x + w11 * d1.x;
            sv[5] = w00 * a1.y + w01 * b1.y + w10 * c1.y + w11 * d1.y;
            sv[6] = w00 * a1.z + w01 * b1.z + w10 * c1.z + w11 * d1.z;
            sv[7] = w00 * a1.w + w01 * b1.w + w10 * c1.w + w11 * d1.w;
#pragma unroll
            for (int j = 0; j < 8; ++j) {
                float s = sv[j];
                unsigned u = __float_as_uint(s);
                short hs = (short)(u >> 16);                      // trunc hi
                float rem = s - bf2f(hs);
                short ls = (short)(__float_as_uint(rem) >> 16);   // trunc lo
                bh[ks][j] = hs;
                bl[ks][j] = ls;
            }
        }

        // MFMA: 2 ks x 4 M-tiles x 3 passes; A-frags direct from global
#pragma unroll
        for (int ks = 0; ks < 2; ++ks) {
            const short* wkh = wbh + k * 4096 + ks * 32;
            const short* wkl = wbl + k * 4096 + ks * 32;
#pragma unroll
            for (int mt = 0; mt < 4; ++mt) {
                bf16x8 ah = *(const bf16x8*)(wkh + mt * 1024);
                bf16x8 al = *(const bf16x8*)(wkl + mt * 1024);
                acc[mt] = __builtin_amdgcn_mfma_f32_16x16x32_bf16(ah, bh[ks], acc[mt], 0, 0, 0);
                acc[mt] = __builtin_amdgcn_mfma_f32_16x16x32_bf16(ah, bl[ks], acc[mt], 0, 0, 0);
                acc[mt] = __builtin_amdgcn_mfma_f32_16x16x32_bf16(al, bh[ks], acc[mt], 0, 0, 0);
            }
        }
    }

    // ---- epilogue: D col=lane&15 -> pixel, row=(lane>>4)*4+r -> oc ----
#pragma unroll
    for (int mt = 0; mt < 4; ++mt) {
#pragma unroll
        for (int r = 0; r < 4; ++r) {
            int oc = mt * 16 + lq * 4 + r;
            out[((size_t)(b * CO_ + oc) * H_ + h) * W_ + wcol] = acc[mt][r];
        }
    }
}

extern "C" void kernel_launch(void* const* d_in, const int* in_sizes, int n_in,
                              void* d_out, int out_size, void* d_ws, size_t ws_size,
                              hipStream_t stream) {
    const float* x  = (const float*)d_in[0];
    const float* wp = (const float*)d_in[1];
    const float* bp = (const float*)d_in[2];
    const float* wd = (const float*)d_in[3];
    float* out = (float*)d_out;
    float* ws  = (float*)d_ws;

    float* xt   = ws + XT_OFF;
    float* off  = ws + OFF_OFF;
    float* wpt2 = ws + WPT2_OFF;
    short* wdh  = (short*)(ws + WDH_OFF);
    short* wdl  = (short*)(ws + WDL_OFF);

    transpose_x_k<<<B_ * H_ * (W_ / 64), 256, 0, stream>>>(x, xt);
    transpose_w_k<<<(K_ * CO_ * C_ + 255) / 256, 256, 0, stream>>>(wd, wp, wdh, wdl, wpt2);
    offset_conv_k<<<B_ * H_ * 2, 256, 0, stream>>>(x, wpt2, bp, off);
    deform_gemm_k<<<B_ * HW_ / 64, 256, 0, stream>>>(xt, off, wdh, wdl, out);
}

// Round 9
// 203.223 us; speedup vs baseline: 1.2592x; 1.2592x over previous
//
#include <hip/hip_runtime.h>

// DCNv1 on MI355X. Deform-GEMM via bf16x3 MFMA (hi/lo split, 3 passes -> ~fp32
// precision). v8: double-buffered LDS + async-stage split (T14): per tap,
// issue tap k+1's global loads FIRST, GEMM tap k (hides gather latency),
// then waitcnt+cvt+ds_write, one barrier. 64KB LDS -> 2 blocks/CU.
// Shapes fixed: B=4, C=64, H=W=128, Cout=64, K=3x3, stride=1, pad=1.

constexpr int B_  = 4;
constexpr int C_  = 64;
constexpr int H_  = 128;
constexpr int W_  = 128;
constexpr int CO_ = 64;
constexpr int K_  = 9;
constexpr int HW_ = H_ * W_;

typedef short bf16x8 __attribute__((ext_vector_type(8)));
typedef float f32x4  __attribute__((ext_vector_type(4)));

#define REP18(M) M(0) M(1) M(2) M(3) M(4) M(5) M(6) M(7) M(8) M(9) M(10) M(11) M(12) M(13) M(14) M(15) M(16) M(17)

// ---------------- workspace layout (float units) ----------------
constexpr size_t XT_OFF   = 0;                                    // NHWC x f32
constexpr size_t OFF_OFF  = XT_OFF + (size_t)B_ * HW_ * C_;       // offsets f32
constexpr size_t WPT2_OFF = OFF_OFF + (size_t)B_ * HW_ * 18;      // w_p^T [c][t][20] f32
constexpr size_t WDH_OFF  = WPT2_OFF + (size_t)C_ * K_ * 20;      // w_d hi bf16 [k][oc][c]
constexpr size_t WDL_OFF  = WDH_OFF + (size_t)K_ * CO_ * C_ / 2;  // w_d lo bf16

__device__ inline short f2bf(float x) {                 // RTN f32->bf16
    unsigned u = __float_as_uint(x);
    return (short)((u + 0x7FFF + ((u >> 16) & 1)) >> 16);
}
__device__ inline float bf2f(short s) {
    return __uint_as_float(((unsigned)(unsigned short)s) << 16);
}

// ---------------- K0a: x NCHW -> NHWC ----------------
__global__ __launch_bounds__(256) void transpose_x_k(const float* __restrict__ x,
                                                     float* __restrict__ xt) {
    __shared__ float tile[64][65];
    int bid = blockIdx.x;           // 1024
    int wt  = bid & 1;
    int h   = (bid >> 1) & 127;
    int b   = bid >> 8;
    int w0  = wt * 64;
    int tid = threadIdx.x;
    int lw = tid & 63, c0 = tid >> 6;
#pragma unroll
    for (int i = 0; i < 16; ++i) {
        int c = c0 * 16 + i;
        tile[c][lw] = x[((b * C_ + c) * H_ + h) * W_ + w0 + lw];
    }
    __syncthreads();
    int lc = tid & 63, wp = tid >> 6;
#pragma unroll
    for (int i = 0; i < 16; ++i) {
        int w = wp * 16 + i;
        xt[((size_t)(b * H_ + h) * W_ + w0 + w) * C_ + lc] = tile[lc][w];
    }
}

// ---------------- K0b: weight prep ----------------
__global__ void transpose_w_k(const float* __restrict__ wd, const float* __restrict__ wp,
                              short* __restrict__ wdh, short* __restrict__ wdl,
                              float* __restrict__ wpt2) {
    int i = blockIdx.x * 256 + threadIdx.x;
    if (i < K_ * CO_ * C_) {               // 36864: [k][oc][c]
        int k  = i / (CO_ * C_);
        int r  = i % (CO_ * C_);
        int oc = r >> 6;
        int c  = r & 63;
        float v = wd[(oc * C_ + c) * K_ + k];
        short h = f2bf(v);
        wdh[i] = h;
        wdl[i] = f2bf(v - bf2f(h));
    }
    if (i < C_ * K_ * 20) {                // 11520
        int j = i % 20;
        int t = (i / 20) % K_;
        int c = i / (20 * K_);
        wpt2[i] = (j < 18) ? wp[((j * C_ + c) * 3 + t / 3) * 3 + (t % 3)] : 0.f;
    }
}

// ---------------- K1: offset conv v5 (unchanged; counters expected next round) ----------------
__global__ __launch_bounds__(256) void offset_conv_k(const float* __restrict__ x,
                                                     const float* __restrict__ wpt2,
                                                     const float* __restrict__ bp,
                                                     float* __restrict__ off) {
    __shared__ float red[4][64][19];
    int tid = threadIdx.x;
    int pix = tid & 63;
    int cqu = __builtin_amdgcn_readfirstlane(tid >> 6);  // wave-uniform 0..3
    int bid = blockIdx.x;
    int w0  = (bid & 1) * 64;
    int h   = (bid >> 1) & 127;
    int b   = bid >> 8;
    int wo  = w0 + pix;

#define DECL_(i) float a##i = 0.f;
    REP18(DECL_)
#undef DECL_

    int c0 = cqu * 16;
    for (int ci = 0; ci < 16; ++ci) {
        int c = c0 + ci;
        const float* xb = x + (size_t)(b * C_ + c) * HW_;   // SGPR base
        const float* wr = wpt2 + c * 180;                   // SGPR base -> s_load
#pragma unroll
        for (int t = 0; t < 9; ++t) {
            int y  = h + t / 3 - 1;
            int xw = wo + (t % 3) - 1;
            float xv = (y >= 0 && y < H_ && xw >= 0 && xw < W_) ? xb[y * W_ + xw] : 0.f;
            const float* wrow = wr + t * 20;
#define FMA_(i) a##i = fmaf(xv, wrow[i], a##i);
            REP18(FMA_)
#undef FMA_
        }
    }
#define ST_(i) red[cqu][pix][i] = a##i;
    REP18(ST_)
#undef ST_
    __syncthreads();

    size_t base = ((size_t)(b * H_ + h) * W_ + w0) * 18;
#pragma unroll
    for (int it = 0; it < 5; ++it) {
        int idx = it * 256 + tid;
        if (idx < 64 * 18) {
            int p = idx / 18, j = idx % 18;
            float s = red[0][p][j] + red[1][p][j] + red[2][p][j] + red[3][p][j] + bp[j];
            off[base + idx] = s;
        }
    }
}

// ---------------- K2: deform sampling + bf16x3 MFMA GEMM v8 ----------------
// Block: 64 pix x 64 oc, 256 thr = 4 waves. Grid = 1024, XCD slab swizzle.
// Double-buffered LDS (samples + weights), async-stage split per tap.
__global__ __launch_bounds__(256, 2) void deform_gemm_k(const float* __restrict__ xt,
                                                        const float* __restrict__ off,
                                                        const short* __restrict__ wdh,
                                                        const short* __restrict__ wdl,
                                                        float* __restrict__ out) {
    __shared__ __align__(16) short s_smp[2][2][64 * 64];  // [buf][hi/lo][pix][c] 32KB
    __shared__ __align__(16) short s_wgt[2][2][64 * 64];  // [buf][hi/lo][oc][c]  32KB

    int tid = threadIdx.x;
    int bid = blockIdx.x;              // 1024
    int xcd = bid & 7;                 // XCD slab swizzle (L2 locality)
    int idx = bid >> 3;                // 0..127
    int b   = xcd >> 1;
    int h   = ((xcd & 1) << 6) | (idx >> 1);
    int w0  = (idx & 1) * 64;

    // staging roles: 4 threads per pixel, 16 channels each
    int pix = tid & 63;
    int c0  = (tid >> 6) * 16;
    // GEMM roles
    int lane = tid & 63;
    int wv   = tid >> 6;
    int l4   = lane & 15;
    int lq   = lane >> 4;
    int ocA  = wv * 16 + l4;
    int koff = lq * 8;                 // fragment k-slice base (within 32-chunk)

    f32x4 acc[4];
#pragma unroll
    for (int i = 0; i < 4; ++i) acc[i] = (f32x4){0.f, 0.f, 0.f, 0.f};

    // preload all 9 taps' offsets (static-indexed)
    const float* ob = off + ((size_t)(b * H_ + h) * W_ + w0 + pix) * 18;
    float2 offs[9];
#pragma unroll
    for (int k = 0; k < 9; ++k) offs[k] = *(const float2*)(ob + 2 * k);

    const float* xb = xt + (size_t)b * HW_ * C_;
    const bf16x8* wdh8 = (const bf16x8*)wdh;
    const bf16x8* wdl8 = (const bf16x8*)wdl;

    // ---- STAGE_LOAD(kk): issue global loads into locals ----
#define STAGE_LOAD(kk)                                                            \
    float2 o2 = offs[kk];                                                         \
    float py = o2.x + (float)(h - 1 + (kk) / 3);                                  \
    float px = o2.y + (float)(w0 + pix - 1 + (kk) % 3);                           \
    float fy = floorf(py), fx = floorf(px);                                       \
    float wy = py - fy, wx = px - fx;                                             \
    int y0 = (int)fy, x0 = (int)fx;                                               \
    int y1 = y0 + 1, x1 = x0 + 1;                                                 \
    float w00 = (1.f - wy) * (1.f - wx);                                          \
    float w01 = (1.f - wy) * wx;                                                  \
    float w10 = wy * (1.f - wx);                                                  \
    float w11 = wy * wx;                                                          \
    bool vy0 = (y0 >= 0) & (y0 < H_), vy1 = (y1 >= 0) & (y1 < H_);                \
    bool vx0 = (x0 >= 0) & (x0 < W_), vx1 = (x1 >= 0) & (x1 < W_);                \
    w00 *= (float)(vy0 & vx0);                                                    \
    w01 *= (float)(vy0 & vx1);                                                    \
    w10 *= (float)(vy1 & vx0);                                                    \
    w11 *= (float)(vy1 & vx1);                                                    \
    int cy0 = min(max(y0, 0), H_ - 1), cy1 = min(max(y1, 0), H_ - 1);             \
    int cx0 = min(max(x0, 0), W_ - 1), cx1 = min(max(x1, 0), W_ - 1);             \
    const float* r00 = xb + ((size_t)cy0 * W_ + cx0) * C_ + c0;                   \
    const float* r01 = xb + ((size_t)cy0 * W_ + cx1) * C_ + c0;                   \
    const float* r10 = xb + ((size_t)cy1 * W_ + cx0) * C_ + c0;                   \
    const float* r11 = xb + ((size_t)cy1 * W_ + cx1) * C_ + c0;                   \
    float4 qa0 = *(const float4*)(r00 + 0),  qa1 = *(const float4*)(r00 + 4);     \
    float4 qa2 = *(const float4*)(r00 + 8),  qa3 = *(const float4*)(r00 + 12);    \
    float4 qb0 = *(const float4*)(r01 + 0),  qb1 = *(const float4*)(r01 + 4);     \
    float4 qb2 = *(const float4*)(r01 + 8),  qb3 = *(const float4*)(r01 + 12);    \
    float4 qc0 = *(const float4*)(r10 + 0),  qc1 = *(const float4*)(r10 + 4);     \
    float4 qc2 = *(const float4*)(r10 + 8),  qc3 = *(const float4*)(r10 + 12);    \
    float4 qd0 = *(const float4*)(r11 + 0),  qd1 = *(const float4*)(r11 + 4);     \
    float4 qd2 = *(const float4*)(r11 + 8),  qd3 = *(const float4*)(r11 + 12);    \
    bf16x8 wqh0 = wdh8[(kk) * 512 + tid], wqh1 = wdh8[(kk) * 512 + 256 + tid];    \
    bf16x8 wql0 = wdl8[(kk) * 512 + tid], wql1 = wdl8[(kk) * 512 + 256 + tid];

    // ---- STAGE_WRITE(dst): cvt + LDS writes (consumes STAGE_LOAD locals) ----
#define STAGE_WRITE(dst)                                                          \
    {                                                                             \
        float sv[16];                                                             \
        const float4 qA[4] = {qa0, qa1, qa2, qa3};                                \
        const float4 qB[4] = {qb0, qb1, qb2, qb3};                                \
        const float4 qC[4] = {qc0, qc1, qc2, qc3};                                \
        const float4 qD[4] = {qd0, qd1, qd2, qd3};                                \
        _Pragma("unroll")                                                         \
        for (int i = 0; i < 4; ++i) {                                             \
            sv[i * 4 + 0] = w00 * qA[i].x + w01 * qB[i].x + w10 * qC[i].x + w11 * qD[i].x; \
            sv[i * 4 + 1] = w00 * qA[i].y + w01 * qB[i].y + w10 * qC[i].y + w11 * qD[i].y; \
            sv[i * 4 + 2] = w00 * qA[i].z + w01 * qB[i].z + w10 * qC[i].z + w11 * qD[i].z; \
            sv[i * 4 + 3] = w00 * qA[i].w + w01 * qB[i].w + w10 * qC[i].w + w11 * qD[i].w; \
        }                                                                         \
        _Pragma("unroll")                                                         \
        for (int i = 0; i < 2; ++i) {                                             \
            bf16x8 hv, lv;                                                        \
            _Pragma("unroll")                                                     \
            for (int j = 0; j < 8; ++j) {                                         \
                float s = sv[i * 8 + j];                                          \
                short hs = (short)(__float_as_uint(s) >> 16);                     \
                hv[j] = hs;                                                       \
                lv[j] = (short)(__float_as_uint(s - bf2f(hs)) >> 16);             \
            }                                                                     \
            int db = (pix * 128 + (c0 + i * 8) * 2) ^ ((pix & 7) << 4);           \
            *(bf16x8*)((char*)s_smp[dst][0] + db) = hv;                           \
            *(bf16x8*)((char*)s_smp[dst][1] + db) = lv;                           \
        }                                                                         \
        _Pragma("unroll")                                                         \
        for (int i = 0; i < 2; ++i) {                                             \
            int e   = (i * 256 + tid) * 8;                                        \
            int row = e >> 6;                                                     \
            int db  = (row * 128 + (e & 63) * 2) ^ ((row & 7) << 4);              \
            *(bf16x8*)((char*)s_wgt[dst][0] + db) = i ? wqh1 : wqh0;              \
            *(bf16x8*)((char*)s_wgt[dst][1] + db) = i ? wql1 : wql0;              \
        }                                                                         \
    }

    // ---- prologue: stage tap 0 ----
    {
        STAGE_LOAD(0)
        STAGE_WRITE(0)
    }
    __syncthreads();

#pragma unroll
    for (int k = 0; k < 9; ++k) {
        int cur = k & 1;
        if (k < 8) {
            STAGE_LOAD(k + 1)                 // loads in flight during GEMM
            // ---- GEMM on buf[cur] ----
#pragma unroll
            for (int ks = 0; ks < 2; ++ks) {
                int ab = (ocA * 128 + (ks * 32 + koff) * 2) ^ ((ocA & 7) << 4);
                bf16x8 ah = *(const bf16x8*)((char*)s_wgt[cur][0] + ab);
                bf16x8 al = *(const bf16x8*)((char*)s_wgt[cur][1] + ab);
#pragma unroll
                for (int nt = 0; nt < 4; ++nt) {
                    int prow = nt * 16 + l4;
                    int bb = (prow * 128 + (ks * 32 + koff) * 2) ^ ((prow & 7) << 4);
                    bf16x8 bh = *(const bf16x8*)((char*)s_smp[cur][0] + bb);
                    bf16x8 bl = *(const bf16x8*)((char*)s_smp[cur][1] + bb);
                    acc[nt] = __builtin_amdgcn_mfma_f32_16x16x32_bf16(ah, bh, acc[nt], 0, 0, 0);
                    acc[nt] = __builtin_amdgcn_mfma_f32_16x16x32_bf16(ah, bl, acc[nt], 0, 0, 0);
                    acc[nt] = __builtin_amdgcn_mfma_f32_16x16x32_bf16(al, bh, acc[nt], 0, 0, 0);
                }
            }
            STAGE_WRITE(cur ^ 1)              // waitcnt + cvt + ds_write
        } else {
            // last tap: GEMM only
#pragma unroll
            for (int ks = 0; ks < 2; ++ks) {
                int ab = (ocA * 128 + (ks * 32 + koff) * 2) ^ ((ocA & 7) << 4);
                bf16x8 ah = *(const bf16x8*)((char*)s_wgt[cur][0] + ab);
                bf16x8 al = *(const bf16x8*)((char*)s_wgt[cur][1] + ab);
#pragma unroll
                for (int nt = 0; nt < 4; ++nt) {
                    int prow = nt * 16 + l4;
                    int bb = (prow * 128 + (ks * 32 + koff) * 2) ^ ((prow & 7) << 4);
                    bf16x8 bh = *(const bf16x8*)((char*)s_smp[cur][0] + bb);
                    bf16x8 bl = *(const bf16x8*)((char*)s_smp[cur][1] + bb);
                    acc[nt] = __builtin_amdgcn_mfma_f32_16x16x32_bf16(ah, bh, acc[nt], 0, 0, 0);
                    acc[nt] = __builtin_amdgcn_mfma_f32_16x16x32_bf16(ah, bl, acc[nt], 0, 0, 0);
                    acc[nt] = __builtin_amdgcn_mfma_f32_16x16x32_bf16(al, bh, acc[nt], 0, 0, 0);
                }
            }
        }
        __syncthreads();
    }

    // ---- epilogue: D col=lane&15 -> pixel, row=(lane>>4)*4+r -> oc ----
#pragma unroll
    for (int nt = 0; nt < 4; ++nt) {
#pragma unroll
        for (int r = 0; r < 4; ++r) {
            int oc = wv * 16 + lq * 4 + r;
            out[((size_t)(b * CO_ + oc) * H_ + h) * W_ + w0 + nt * 16 + l4] = acc[nt][r];
        }
    }
#undef STAGE_LOAD
#undef STAGE_WRITE
}

extern "C" void kernel_launch(void* const* d_in, const int* in_sizes, int n_in,
                              void* d_out, int out_size, void* d_ws, size_t ws_size,
                              hipStream_t stream) {
    const float* x  = (const float*)d_in[0];
    const float* wp = (const float*)d_in[1];
    const float* bp = (const float*)d_in[2];
    const float* wd = (const float*)d_in[3];
    float* out = (float*)d_out;
    float* ws  = (float*)d_ws;

    float* xt   = ws + XT_OFF;
    float* off  = ws + OFF_OFF;
    float* wpt2 = ws + WPT2_OFF;
    short* wdh  = (short*)(ws + WDH_OFF);
    short* wdl  = (short*)(ws + WDL_OFF);

    transpose_x_k<<<B_ * H_ * (W_ / 64), 256, 0, stream>>>(x, xt);
    transpose_w_k<<<(K_ * CO_ * C_ + 255) / 256, 256, 0, stream>>>(wd, wp, wdh, wdl, wpt2);
    offset_conv_k<<<B_ * H_ * 2, 256, 0, stream>>>(x, wpt2, bp, off);
    deform_gemm_k<<<B_ * HW_ / 64, 256, 0, stream>>>(xt, off, wdh, wdl, out);
}

// Round 10
// 200.467 us; speedup vs baseline: 1.2765x; 1.0137x over previous
//
#include <hip/hip_runtime.h>

// DCNv1 on MI355X. v9:
//  - deform GEMM: bf16x3 MFMA, samples dbuf in LDS (32KB), WEIGHT FRAGS FROM
//    GLOBAL->REGS (no weight LDS) -> 4 blocks/CU.
//  - offset conv: MFMA version (x pre-split to bf16 hi/lo), ws_size-guarded
//    with the VALU version as fallback.
// Shapes fixed: B=4, C=64, H=W=128, Cout=64, K=3x3, stride=1, pad=1.

constexpr int B_  = 4;
constexpr int C_  = 64;
constexpr int H_  = 128;
constexpr int W_  = 128;
constexpr int CO_ = 64;
constexpr int K_  = 9;
constexpr int HW_ = H_ * W_;

typedef short bf16x8 __attribute__((ext_vector_type(8)));
typedef float f32x4  __attribute__((ext_vector_type(4)));

#define REP18(M) M(0) M(1) M(2) M(3) M(4) M(5) M(6) M(7) M(8) M(9) M(10) M(11) M(12) M(13) M(14) M(15) M(16) M(17)

// ---------------- workspace layout (float units) ----------------
constexpr size_t XT_OFF   = 0;                                   // NHWC x f32 (4,194,304)
constexpr size_t OFF_OFF  = XT_OFF + (size_t)B_ * HW_ * C_;      // offsets (1,179,648)
constexpr size_t WDH_OFF  = OFF_OFF + (size_t)B_ * HW_ * 18;     // w_d hi bf16 [k][oc][c] (18,432 fl)
constexpr size_t WDL_OFF  = WDH_OFF + (size_t)K_ * CO_ * C_ / 2; // w_d lo
constexpr size_t WPT2_OFF = WDL_OFF + (size_t)K_ * CO_ * C_ / 2; // w_p^T [c][t][20] f32 (11,520)
constexpr size_t WPBH_OFF = WPT2_OFF + (size_t)C_ * K_ * 20;     // w_p mfma hi [18][32][32] bf16 (9,216 fl)
constexpr size_t WPBL_OFF = WPBH_OFF + 9216;                     // w_p mfma lo
constexpr size_t XH_OFF   = WPBL_OFF + 9216;                     // x hi bf16 NHWC (2,097,152 fl)
constexpr size_t XL_OFF   = XH_OFF + (size_t)B_ * HW_ * C_ / 2;  // x lo bf16
constexpr size_t WS_NEED  = (XL_OFF + (size_t)B_ * HW_ * C_ / 2) * 4;  // bytes (~38.5MB)

__device__ inline short f2bf(float x) {                 // RTN f32->bf16
    unsigned u = __float_as_uint(x);
    return (short)((u + 0x7FFF + ((u >> 16) & 1)) >> 16);
}
__device__ inline float bf2f(short s) {
    return __uint_as_float(((unsigned)(unsigned short)s) << 16);
}

// ---------------- K0a: x NCHW -> NHWC (f32 + optional bf16 hi/lo) ----------------
__global__ __launch_bounds__(256) void transpose_x_k(const float* __restrict__ x,
                                                     float* __restrict__ xt,
                                                     short* __restrict__ xh,
                                                     short* __restrict__ xl,
                                                     int wbf) {
    __shared__ float tile[64][65];
    int bid = blockIdx.x;           // 1024
    int wt  = bid & 1;
    int h   = (bid >> 1) & 127;
    int b   = bid >> 8;
    int w0  = wt * 64;
    int tid = threadIdx.x;
    int lw = tid & 63, c0 = tid >> 6;
#pragma unroll
    for (int i = 0; i < 16; ++i) {
        int c = c0 * 16 + i;
        tile[c][lw] = x[((b * C_ + c) * H_ + h) * W_ + w0 + lw];
    }
    __syncthreads();
    int lc = tid & 63, wp = tid >> 6;
#pragma unroll
    for (int i = 0; i < 16; ++i) {
        int w = wp * 16 + i;
        size_t di = ((size_t)(b * H_ + h) * W_ + w0 + w) * C_ + lc;
        float v = tile[lc][w];
        xt[di] = v;
        if (wbf) {
            short hs = (short)(__float_as_uint(v) >> 16);          // trunc hi
            xh[di] = hs;
            xl[di] = (short)(__float_as_uint(v - bf2f(hs)) >> 16); // trunc lo
        }
    }
}

// ---------------- K0b: weight prep ----------------
__global__ void transpose_w_k(const float* __restrict__ wd, const float* __restrict__ wp,
                              short* __restrict__ wdh, short* __restrict__ wdl,
                              float* __restrict__ wpt2,
                              short* __restrict__ wpbh, short* __restrict__ wpbl) {
    int i = blockIdx.x * 256 + threadIdx.x;
    if (i < K_ * CO_ * C_) {               // 36864: [k][oc][c]
        int k  = i / (CO_ * C_);
        int r  = i % (CO_ * C_);
        int oc = r >> 6;
        int c  = r & 63;
        float v = wd[(oc * C_ + c) * K_ + k];
        short h = f2bf(v);
        wdh[i] = h;
        wdl[i] = f2bf(v - bf2f(h));
    }
    if (i < C_ * K_ * 20) {                // 11520 (fallback path)
        int j = i % 20;
        int t = (i / 20) % K_;
        int c = i / (20 * K_);
        wpt2[i] = (j < 18) ? wp[((j * C_ + c) * 3 + t / 3) * 3 + (t % 3)] : 0.f;
    }
    if (i < 18 * 32 * 32) {                // 18432: [kstep][oc(pad32)][c32]
        int kstep = i >> 10;               // t*2+chalf
        int r     = i & 1023;
        int oc    = r >> 5;
        int c5    = r & 31;
        int t     = kstep >> 1;
        int c     = (kstep & 1) * 32 + c5;
        float v = (oc < 18) ? wp[((oc * C_ + c) * 3 + t / 3) * 3 + (t % 3)] : 0.f;
        short h = f2bf(v);
        wpbh[i] = h;
        wpbl[i] = f2bf(v - bf2f(h));
    }
}

// ---------------- K1a: offset conv via MFMA (big-ws path) ----------------
// Block = one row (128 px), 4 waves x 32 px. A = w_p [32oc(18 valid)][576k]
// hi/lo, B = x bf16 hi/lo at shifted integer positions (no staging VALU).
// Per kstep (t,chalf): 2 mt x 2 nt x 3 passes = 12 MFMA; 18 ksteps = 216/wave.
__global__ __launch_bounds__(256) void offset_mfma_k(const short* __restrict__ xh,
                                                     const short* __restrict__ xl,
                                                     const short* __restrict__ wpbh,
                                                     const short* __restrict__ wpbl,
                                                     const float* __restrict__ bp,
                                                     float* __restrict__ off) {
    int tid  = threadIdx.x;
    int bid  = blockIdx.x;             // 512
    int xcd  = bid & 7;                // XCD slab swizzle
    int b    = xcd >> 1;
    int h    = ((xcd & 1) << 6) | (bid >> 3);
    int lane = tid & 63;
    int wv   = tid >> 6;
    int l4   = lane & 15;
    int lq   = lane >> 4;
    int px0  = wv * 32;

    const short* xhb = xh + (size_t)b * HW_ * C_;
    const short* xlb = xl + (size_t)b * HW_ * C_;

    f32x4 acc[2][2];                   // [mt][nt]
#pragma unroll
    for (int i = 0; i < 2; ++i)
#pragma unroll
        for (int j = 0; j < 2; ++j) acc[i][j] = (f32x4){0.f, 0.f, 0.f, 0.f};

    const bf16x8 zf = (bf16x8){0, 0, 0, 0, 0, 0, 0, 0};

#pragma unroll
    for (int t = 0; t < 9; ++t) {
        int ty = t / 3, tx = t % 3;
        int y  = h + ty - 1;
        bool yv = (y >= 0) & (y < H_);
        int yc = min(max(y, 0), H_ - 1);
#pragma unroll
        for (int chalf = 0; chalf < 2; ++chalf) {
            int kstep = t * 2 + chalf;
            const short* abase = wpbh + kstep * 1024 + l4 * 32 + lq * 8;
            const short* abasl = wpbl + kstep * 1024 + l4 * 32 + lq * 8;
            bf16x8 a0h = *(const bf16x8*)(abase);
            bf16x8 a0l = *(const bf16x8*)(abasl);
            bf16x8 a1h = *(const bf16x8*)(abase + 512);   // rows 16..31 (pad>=18)
            bf16x8 a1l = *(const bf16x8*)(abasl + 512);
#pragma unroll
            for (int nt = 0; nt < 2; ++nt) {
                int p = px0 + nt * 16 + l4 + tx - 1;
                bool valid = yv & (p >= 0) & (p < W_);
                int pc = min(max(p, 0), W_ - 1);
                size_t ai = ((size_t)yc * W_ + pc) * C_ + chalf * 32 + lq * 8;
                bf16x8 bh = *(const bf16x8*)(xhb + ai);
                bf16x8 bl = *(const bf16x8*)(xlb + ai);
                if (!valid) { bh = zf; bl = zf; }
                acc[0][nt] = __builtin_amdgcn_mfma_f32_16x16x32_bf16(a0h, bh, acc[0][nt], 0, 0, 0);
                acc[0][nt] = __builtin_amdgcn_mfma_f32_16x16x32_bf16(a0h, bl, acc[0][nt], 0, 0, 0);
                acc[0][nt] = __builtin_amdgcn_mfma_f32_16x16x32_bf16(a0l, bh, acc[0][nt], 0, 0, 0);
                acc[1][nt] = __builtin_amdgcn_mfma_f32_16x16x32_bf16(a1h, bh, acc[1][nt], 0, 0, 0);
                acc[1][nt] = __builtin_amdgcn_mfma_f32_16x16x32_bf16(a1h, bl, acc[1][nt], 0, 0, 0);
                acc[1][nt] = __builtin_amdgcn_mfma_f32_16x16x32_bf16(a1l, bh, acc[1][nt], 0, 0, 0);
            }
        }
    }

    // D: col=l4 -> pixel, row=lq*4+r (+16 for mt1) -> output channel j
    size_t rbase = ((size_t)(b * H_ + h) * W_);
#pragma unroll
    for (int mt = 0; mt < 2; ++mt)
#pragma unroll
        for (int nt = 0; nt < 2; ++nt)
#pragma unroll
            for (int r = 0; r < 4; ++r) {
                int j = mt * 16 + lq * 4 + r;
                if (j < 18) {
                    int p = px0 + nt * 16 + l4;
                    off[(rbase + p) * 18 + j] = acc[mt][nt][r] + bp[j];
                }
            }
}

// ---------------- K1b: offset conv VALU (fallback if ws too small) ----------------
__global__ __launch_bounds__(256) void offset_conv_k(const float* __restrict__ x,
                                                     const float* __restrict__ wpt2,
                                                     const float* __restrict__ bp,
                                                     float* __restrict__ off) {
    __shared__ float red[4][64][19];
    int tid = threadIdx.x;
    int pix = tid & 63;
    int cqu = __builtin_amdgcn_readfirstlane(tid >> 6);
    int bid = blockIdx.x;
    int w0  = (bid & 1) * 64;
    int h   = (bid >> 1) & 127;
    int b   = bid >> 8;
    int wo  = w0 + pix;

#define DECL_(i) float a##i = 0.f;
    REP18(DECL_)
#undef DECL_

    int c0 = cqu * 16;
    for (int ci = 0; ci < 16; ++ci) {
        int c = c0 + ci;
        const float* xb = x + (size_t)(b * C_ + c) * HW_;
        const float* wr = wpt2 + c * 180;
#pragma unroll
        for (int t = 0; t < 9; ++t) {
            int y  = h + t / 3 - 1;
            int xw = wo + (t % 3) - 1;
            float xv = (y >= 0 && y < H_ && xw >= 0 && xw < W_) ? xb[y * W_ + xw] : 0.f;
            const float* wrow = wr + t * 20;
#define FMA_(i) a##i = fmaf(xv, wrow[i], a##i);
            REP18(FMA_)
#undef FMA_
        }
    }
#define ST_(i) red[cqu][pix][i] = a##i;
    REP18(ST_)
#undef ST_
    __syncthreads();

    size_t base = ((size_t)(b * H_ + h) * W_ + w0) * 18;
#pragma unroll
    for (int it = 0; it < 5; ++it) {
        int idx = it * 256 + tid;
        if (idx < 64 * 18) {
            int p = idx / 18, j = idx % 18;
            float s = red[0][p][j] + red[1][p][j] + red[2][p][j] + red[3][p][j] + bp[j];
            off[base + idx] = s;
        }
    }
}

// ---------------- K2: deform sampling + bf16x3 MFMA GEMM v9 ----------------
// Samples dbuf in LDS (32KB); weight A-frags straight from global into regs
// (prefetched one tap ahead). 1 barrier/tap. Target 4 blocks/CU.
__global__ __launch_bounds__(256, 4) void deform_gemm_k(const float* __restrict__ xt,
                                                        const float* __restrict__ off,
                                                        const short* __restrict__ wdh,
                                                        const short* __restrict__ wdl,
                                                        float* __restrict__ out) {
    __shared__ __align__(16) short s_smp[2][2][64 * 64];  // [buf][hi/lo][pix][c] 32KB

    int tid = threadIdx.x;
    int bid = blockIdx.x;              // 1024
    int xcd = bid & 7;                 // XCD slab swizzle
    int idx = bid >> 3;                // 0..127
    int b   = xcd >> 1;
    int h   = ((xcd & 1) << 6) | (idx >> 1);
    int w0  = (idx & 1) * 64;

    int pix = tid & 63;
    int c0  = (tid >> 6) * 16;
    int lane = tid & 63;
    int wv   = tid >> 6;
    int l4   = lane & 15;
    int lq   = lane >> 4;
    int ocA  = wv * 16 + l4;
    int koff = lq * 8;

    f32x4 acc[4];
#pragma unroll
    for (int i = 0; i < 4; ++i) acc[i] = (f32x4){0.f, 0.f, 0.f, 0.f};

    const float* ob = off + ((size_t)(b * H_ + h) * W_ + w0 + pix) * 18;
    const float* xb = xt + (size_t)b * HW_ * C_;
    const short* wfh = wdh + ocA * 64 + koff;   // per-lane A-frag base
    const short* wfl = wdl + ocA * 64 + koff;

#define SAMP_LOAD(kk)                                                             \
    float2 o2 = *(const float2*)(ob + 2 * (kk));                                  \
    float py = o2.x + (float)(h - 1 + (kk) / 3);                                  \
    float px = o2.y + (float)(w0 + pix - 1 + (kk) % 3);                           \
    float fy = floorf(py), fx = floorf(px);                                       \
    float wy = py - fy, wx = px - fx;                                             \
    int y0 = (int)fy, x0 = (int)fx;                                               \
    int y1 = y0 + 1, x1 = x0 + 1;                                                 \
    float w00 = (1.f - wy) * (1.f - wx);                                          \
    float w01 = (1.f - wy) * wx;                                                  \
    float w10 = wy * (1.f - wx);                                                  \
    float w11 = wy * wx;                                                          \
    bool vy0 = (y0 >= 0) & (y0 < H_), vy1 = (y1 >= 0) & (y1 < H_);                \
    bool vx0 = (x0 >= 0) & (x0 < W_), vx1 = (x1 >= 0) & (x1 < W_);                \
    w00 *= (float)(vy0 & vx0);                                                    \
    w01 *= (float)(vy0 & vx1);                                                    \
    w10 *= (float)(vy1 & vx0);                                                    \
    w11 *= (float)(vy1 & vx1);                                                    \
    int cy0 = min(max(y0, 0), H_ - 1), cy1 = min(max(y1, 0), H_ - 1);             \
    int cx0 = min(max(x0, 0), W_ - 1), cx1 = min(max(x1, 0), W_ - 1);             \
    const float* r00 = xb + ((size_t)cy0 * W_ + cx0) * C_ + c0;                   \
    const float* r01 = xb + ((size_t)cy0 * W_ + cx1) * C_ + c0;                   \
    const float* r10 = xb + ((size_t)cy1 * W_ + cx0) * C_ + c0;                   \
    const float* r11 = xb + ((size_t)cy1 * W_ + cx1) * C_ + c0;                   \
    float4 qa0 = *(const float4*)(r00 + 0),  qa1 = *(const float4*)(r00 + 4);     \
    float4 qa2 = *(const float4*)(r00 + 8),  qa3 = *(const float4*)(r00 + 12);    \
    float4 qb0 = *(const float4*)(r01 + 0),  qb1 = *(const float4*)(r01 + 4);     \
    float4 qb2 = *(const float4*)(r01 + 8),  qb3 = *(const float4*)(r01 + 12);    \
    float4 qc0 = *(const float4*)(r10 + 0),  qc1 = *(const float4*)(r10 + 4);     \
    float4 qc2 = *(const float4*)(r10 + 8),  qc3 = *(const float4*)(r10 + 12);    \
    float4 qd0 = *(const float4*)(r11 + 0),  qd1 = *(const float4*)(r11 + 4);     \
    float4 qd2 = *(const float4*)(r11 + 8),  qd3 = *(const float4*)(r11 + 12);

#define SAMP_WRITE(dst)                                                           \
    {                                                                             \
        float sv[16];                                                             \
        const float4 qA[4] = {qa0, qa1, qa2, qa3};                                \
        const float4 qB[4] = {qb0, qb1, qb2, qb3};                                \
        const float4 qC[4] = {qc0, qc1, qc2, qc3};                                \
        const float4 qD[4] = {qd0, qd1, qd2, qd3};                                \
        _Pragma("unroll")                                                         \
        for (int i = 0; i < 4; ++i) {                                             \
            sv[i * 4 + 0] = w00 * qA[i].x + w01 * qB[i].x + w10 * qC[i].x + w11 * qD[i].x; \
            sv[i * 4 + 1] = w00 * qA[i].y + w01 * qB[i].y + w10 * qC[i].y + w11 * qD[i].y; \
            sv[i * 4 + 2] = w00 * qA[i].z + w01 * qB[i].z + w10 * qC[i].z + w11 * qD[i].z; \
            sv[i * 4 + 3] = w00 * qA[i].w + w01 * qB[i].w + w10 * qC[i].w + w11 * qD[i].w; \
        }                                                                         \
        _Pragma("unroll")                                                         \
        for (int i = 0; i < 2; ++i) {                                             \
            bf16x8 hv, lv;                                                        \
            _Pragma("unroll")                                                     \
            for (int j = 0; j < 8; ++j) {                                         \
                float s = sv[i * 8 + j];                                          \
                short hs = (short)(__float_as_uint(s) >> 16);                     \
                hv[j] = hs;                                                       \
                lv[j] = (short)(__float_as_uint(s - bf2f(hs)) >> 16);             \
            }                                                                     \
            int db = (pix * 128 + (c0 + i * 8) * 2) ^ ((pix & 7) << 4);           \
            *(bf16x8*)((char*)s_smp[dst][0] + db) = hv;                           \
            *(bf16x8*)((char*)s_smp[dst][1] + db) = lv;                           \
        }                                                                         \
    }

#define GEMM_TAP(cur)                                                             \
    _Pragma("unroll")                                                             \
    for (int ks = 0; ks < 2; ++ks) {                                              \
        bf16x8 ah = ks ? cw1h : cw0h;                                             \
        bf16x8 al = ks ? cw1l : cw0l;                                             \
        _Pragma("unroll")                                                         \
        for (int nt = 0; nt < 4; ++nt) {                                          \
            int prow = nt * 16 + l4;                                              \
            int bb = (prow * 128 + (ks * 32 + koff) * 2) ^ ((prow & 7) << 4);     \
            bf16x8 bh = *(const bf16x8*)((char*)s_smp[cur][0] + bb);              \
            bf16x8 bl = *(const bf16x8*)((char*)s_smp[cur][1] + bb);              \
            acc[nt] = __builtin_amdgcn_mfma_f32_16x16x32_bf16(ah, bh, acc[nt], 0, 0, 0); \
            acc[nt] = __builtin_amdgcn_mfma_f32_16x16x32_bf16(ah, bl, acc[nt], 0, 0, 0); \
            acc[nt] = __builtin_amdgcn_mfma_f32_16x16x32_bf16(al, bh, acc[nt], 0, 0, 0); \
        }                                                                         \
    }

    // prologue: tap-0 weights + samples
    bf16x8 cw0h = *(const bf16x8*)(wfh);
    bf16x8 cw1h = *(const bf16x8*)(wfh + 32);
    bf16x8 cw0l = *(const bf16x8*)(wfl);
    bf16x8 cw1l = *(const bf16x8*)(wfl + 32);
    {
        SAMP_LOAD(0)
        SAMP_WRITE(0)
    }
    __syncthreads();

#pragma unroll
    for (int k = 0; k < 9; ++k) {
        int cur = k & 1;
        if (k < 8) {
            SAMP_LOAD(k + 1)
            bf16x8 nw0h = *(const bf16x8*)(wfh + (k + 1) * 4096);
            bf16x8 nw1h = *(const bf16x8*)(wfh + (k + 1) * 4096 + 32);
            bf16x8 nw0l = *(const bf16x8*)(wfl + (k + 1) * 4096);
            bf16x8 nw1l = *(const bf16x8*)(wfl + (k + 1) * 4096 + 32);
            GEMM_TAP(cur)
            SAMP_WRITE(cur ^ 1)
            cw0h = nw0h; cw1h = nw1h; cw0l = nw0l; cw1l = nw1l;
        } else {
            GEMM_TAP(cur)
        }
        __syncthreads();
    }

    // epilogue: D col=l4 -> pixel, row=lq*4+r -> oc (within wave's 16-oc tile)
#pragma unroll
    for (int nt = 0; nt < 4; ++nt) {
#pragma unroll
        for (int r = 0; r < 4; ++r) {
            int oc = wv * 16 + lq * 4 + r;
            out[((size_t)(b * CO_ + oc) * H_ + h) * W_ + w0 + nt * 16 + l4] = acc[nt][r];
        }
    }
#undef SAMP_LOAD
#undef SAMP_WRITE
#undef GEMM_TAP
}

extern "C" void kernel_launch(void* const* d_in, const int* in_sizes, int n_in,
                              void* d_out, int out_size, void* d_ws, size_t ws_size,
                              hipStream_t stream) {
    const float* x  = (const float*)d_in[0];
    const float* wp = (const float*)d_in[1];
    const float* bp = (const float*)d_in[2];
    const float* wd = (const float*)d_in[3];
    float* out = (float*)d_out;
    float* ws  = (float*)d_ws;

    float* xt   = ws + XT_OFF;
    float* off  = ws + OFF_OFF;
    short* wdh  = (short*)(ws + WDH_OFF);
    short* wdl  = (short*)(ws + WDL_OFF);
    float* wpt2 = ws + WPT2_OFF;
    short* wpbh = (short*)(ws + WPBH_OFF);
    short* wpbl = (short*)(ws + WPBL_OFF);
    short* xh   = (short*)(ws + XH_OFF);
    short* xl   = (short*)(ws + XL_OFF);

    int big = (ws_size >= WS_NEED) ? 1 : 0;   // ws_size constant across calls -> graph-safe

    transpose_x_k<<<B_ * H_ * (W_ / 64), 256, 0, stream>>>(x, xt, xh, xl, big);
    transpose_w_k<<<(K_ * CO_ * C_ + 255) / 256, 256, 0, stream>>>(wd, wp, wdh, wdl,
                                                                   wpt2, wpbh, wpbl);
    if (big) {
        offset_mfma_k<<<B_ * H_, 256, 0, stream>>>(xh, xl, wpbh, wpbl, bp, off);
    } else {
        offset_conv_k<<<B_ * H_ * 2, 256, 0, stream>>>(x, wpt2, bp, off);
    }
    deform_gemm_k<<<B_ * HW_ / 64, 256, 0, stream>>>(xt, off, wdh, wdl, out);
}